// Round 9
// baseline (232.314 us; speedup 1.0000x reference)
//
#include <hip/hip_runtime.h>
#include <hip/hip_bf16.h>
#include <stdint.h>
#include <stddef.h>

typedef unsigned short ushortT;
typedef __attribute__((ext_vector_type(8))) short bf16x8s;   // 8 bf16, 4 VGPRs
typedef __attribute__((ext_vector_type(4))) float f32x4;
typedef __attribute__((ext_vector_type(16))) float f32x16;

// ---------------------------------------------------------------- helpers ---

__device__ __forceinline__ short f2bf(float f) {
  unsigned u = __float_as_uint(f);
  u += 0x7FFFu + ((u >> 16) & 1u);     // RNE; finite inputs
  return (short)(u >> 16);
}

__device__ __forceinline__ bf16x8s cvt8(const float* src) {
  const float4* p = (const float4*)src;
  float4 a = p[0], b = p[1];
  bf16x8s r;
  r[0] = f2bf(a.x); r[1] = f2bf(a.y); r[2] = f2bf(a.z); r[3] = f2bf(a.w);
  r[4] = f2bf(b.x); r[5] = f2bf(b.y); r[6] = f2bf(b.z); r[7] = f2bf(b.w);
  return r;
}

// packed f32x2 -> bf16x2 (RNE), one instruction
__device__ __forceinline__ unsigned cvtpk_bf16(float lo, float hi) {
  unsigned r;
  asm("v_cvt_pk_bf16_f32 %0, %1, %2" : "=v"(r) : "v"(lo), "v"(hi));
  return r;
}

// gfx950 half-wave swap: a' = [a_lo | b_lo], b' = [a_hi | b_hi]
__device__ __forceinline__ void permlane32_swap(unsigned& a, unsigned& b) {
  asm("v_permlane32_swap_b32 %0, %1" : "+v"(a), "+v"(b));
}

__device__ __forceinline__ void load_lds16(const ushortT* g, ushortT* l) {
  __builtin_amdgcn_global_load_lds(
      (const __attribute__((address_space(1))) void*)(g),
      (__attribute__((address_space(3))) void*)(l), 16, 0, 0);
}

// ------------------------------------------------------------ prep kernel ---
// z=0..3: transpose Wq/Wk/Wv/Wo (fp32 -> bf16); z=4..6: convert q/k/v.
// r9: W-tile path vectorized — float4 loads, ushort4 transposed stores
// (4x fewer memory instructions than the scalar version).
__global__ __launch_bounds__(256)
void prep(const float* __restrict__ q, const float* __restrict__ k,
          const float* __restrict__ v,
          const float* __restrict__ Wq, const float* __restrict__ Wk,
          const float* __restrict__ Wv, const float* __restrict__ Wo,
          ushortT* __restrict__ Qc, ushortT* __restrict__ Kc,
          ushortT* __restrict__ Vc, ushortT* __restrict__ Wt)
{
  const int z = blockIdx.z;
  if (z < 4) {
    if (blockIdx.x >= 1024) return;            // 32x32 tiles over 1024^2
    __shared__ __align__(16) ushortT t[32][36]; // pitch 72B: 8B-aligned rows
    const float* W = (z == 0) ? Wq : (z == 1) ? Wk : (z == 2) ? Wv : Wo;
    ushortT* dst = Wt + (size_t)z * 1024 * 1024;
    const int x = (blockIdx.x & 31) * 32, y = (blockIdx.x >> 5) * 32;
    const int r  = threadIdx.x >> 3;           // 0..31
    const int c4 = (threadIdx.x & 7) << 2;     // 0,4,..,28
    const float4 wv = *(const float4*)(W + (size_t)(y + r) * 1024 + x + c4);
    ushort4 tv;
    tv.x = (ushortT)f2bf(wv.x); tv.y = (ushortT)f2bf(wv.y);
    tv.z = (ushortT)f2bf(wv.z); tv.w = (ushortT)f2bf(wv.w);
    *(ushort4*)&t[r][c4] = tv;
    __syncthreads();
    ushort4 o;
    o.x = t[c4 + 0][r]; o.y = t[c4 + 1][r];
    o.z = t[c4 + 2][r]; o.w = t[c4 + 3][r];
    *(ushort4*)(dst + (size_t)(x + r) * 1024 + y + c4) = o;
  } else {
    const float* src = (z == 4) ? q : (z == 5) ? k : v;
    ushortT* dst = (z == 4) ? Qc : (z == 5) ? Kc : Vc;
    const size_t i8 = ((size_t)blockIdx.x * 256 + threadIdx.x) * 8;
    *(bf16x8s*)(dst + i8) = cvt8(src + i8);
  }
}

// --------------------------------------------------------------- GEMM core --
// r9: BK=64 (half the barrier/drain crossings of BK=32; LDS 32KB, fine at
// 2-3 blocks/CU — m132's BK=128 64KB occupancy cliff avoided). [128][64]
// naive layout would put all 16 frag lanes of a quad in one 4-bank group
// (row stride == 0 mod 32 dwords); fixed with the XOR-chunk swizzle done the
// global_load_lds-legal way (m173/rule #21): LINEAR LDS dest, pre-swizzled
// GLOBAL source (gko = (pc^(row&7))<<3), frag reads apply the same XOR
// (co = ((kk*4+quad)^(lr&7))<<3) -> enumerated 8 lanes/4-bank group,
// distinct addresses = 8-cycle minimum, conflict-free.
__device__ __forceinline__ void gemm_core_128_bk64(
    const ushortT* __restrict__ A, const ushortT* __restrict__ Bt,
    int K, ushortT* As, ushortT* Bs, f32x4 (&acc)[4][4], int m0, int n0)
{
  const int tid  = threadIdx.x;
  const int wave = tid >> 6, lane = tid & 63;
  const int wm = (wave & 1) << 6;
  const int wn = (wave >> 1) << 6;
  const int lr = lane & 15;
  const int quad = (lane >> 4) & 3;

#pragma unroll
  for (int mi = 0; mi < 4; ++mi)
#pragma unroll
    for (int ni = 0; ni < 4; ++ni)
      acc[mi][ni] = (f32x4){0.f, 0.f, 0.f, 0.f};

  for (int k0 = 0; k0 < K; k0 += 64) {
    __syncthreads();
#pragma unroll
    for (int i = 0; i < 4; ++i) {
      const int cc  = tid + (i << 8);          // 0..1023
      const int row = cc >> 3;                 // 0..127
      const int pc  = cc & 7;                  // physical chunk
      const int gko = ((pc ^ (row & 7)) << 3); // pre-swizzled global chunk
      load_lds16(A  + (size_t)(m0 + row) * K + k0 + gko, As + cc * 8);
      load_lds16(Bt + (size_t)(n0 + row) * K + k0 + gko, Bs + cc * 8);
    }
    __syncthreads();

#pragma unroll
    for (int kk = 0; kk < 2; ++kk) {
      const int co = (((kk * 4 + quad) ^ (lr & 7)) << 3);
      bf16x8s af[4], bfr[4];
#pragma unroll
      for (int i = 0; i < 4; ++i)
        af[i] = *(const bf16x8s*)(As + (wm + i * 16 + lr) * 64 + co);
#pragma unroll
      for (int i = 0; i < 4; ++i)
        bfr[i] = *(const bf16x8s*)(Bs + (wn + i * 16 + lr) * 64 + co);

#pragma unroll
      for (int mi = 0; mi < 4; ++mi)
#pragma unroll
        for (int ni = 0; ni < 4; ++ni)
          acc[mi][ni] = __builtin_amdgcn_mfma_f32_16x16x32_bf16(
              af[mi], bfr[ni], acc[mi][ni], 0, 0, 0);
    }
  }
}

// ------------------------------------------------------ projection GEMMs ---
__global__ __launch_bounds__(256)
void proj_gemm(const ushortT* __restrict__ Qc, const ushortT* __restrict__ Kc,
               const ushortT* __restrict__ Vc, const ushortT* __restrict__ WtAll,
               const float* __restrict__ bq, const float* __restrict__ bk,
               const float* __restrict__ bv,
               ushortT* __restrict__ Qh, ushortT* __restrict__ Kh,
               ushortT* __restrict__ Vt)
{
  __shared__ __align__(16) ushortT As[128 * 64];
  __shared__ __align__(16) ushortT Bs[128 * 64];
  const int which = blockIdx.z;
  const ushortT* A  = (which == 0) ? Qc : (which == 1) ? Kc : Vc;
  const ushortT* Bt = WtAll + (size_t)which * 1024 * 1024;
  const float* bias = (which == 0) ? bq : (which == 1) ? bk : bv;
  const int m0 = blockIdx.x * 128, n0 = blockIdx.y * 128;

  f32x4 acc[4][4];
  gemm_core_128_bk64(A, Bt, 1024, As, Bs, acc, m0, n0);

  const int lane = threadIdx.x & 63, wave = threadIdx.x >> 6;
  const int wm = (wave & 1) << 6, wn = (wave >> 1) << 6;
  const int lr = lane & 15, quad = lane >> 4;
  const float QSCALE = 0.18033688011112042f;   // log2(e) / sqrt(64)

#pragma unroll
  for (int ni = 0; ni < 4; ++ni) {
    const int n = n0 + wn + ni * 16 + lr;
    const float bias_v = bias[n];
    const int h = n >> 6, d = n & 63;
#pragma unroll
    for (int mi = 0; mi < 4; ++mi) {
#pragma unroll
      for (int r = 0; r < 4; ++r) {
        const int m = m0 + wm + mi * 16 + quad * 4 + r;
        const int b = m >> 11, l = m & 2047;
        float val = acc[mi][ni][r] + bias_v;
        if (which == 0) val *= QSCALE;
        const ushortT o = (ushortT)f2bf(val);
        const size_t bh = (size_t)(b * 16 + h);
        if (which == 0)      Qh[(bh * 2048 + l) * 64 + d] = o;
        else if (which == 1) Kh[(bh * 2048 + l) * 64 + d] = o;
        else                 Vt[(bh * 64 + d) * 2048 + l] = o;
      }
    }
  }
}

// ------------------------------------------------------- flash attention ---
// r8 kernel verbatim (validated 53 us): 32x32x16 MFMAs, swapped QK^T,
// in-register P via cvt_pk + permlane32_swap (T12), pitch-64 XOR K/V LDS.
__global__ __launch_bounds__(256)
void attn_kernel(const ushortT* __restrict__ Qh, const ushortT* __restrict__ Kh,
                 const ushortT* __restrict__ Vt, ushortT* __restrict__ Ob)
{
  const int b = blockIdx.z, h = blockIdx.y, qt = blockIdx.x;
  const int bh = b * 16 + h;
  const int wave = threadIdx.x >> 6, lane = threadIdx.x & 63;
  const int l31 = lane & 31, hi = lane >> 5, rk7 = l31 & 7;
  const int q0 = qt * 128 + wave * 32;

  const ushortT* Q = Qh + ((size_t)bh * 2048 + q0) * 64;
  const ushortT* K = Kh + (size_t)bh * 2048 * 64;
  const ushortT* V = Vt + (size_t)bh * 64 * 2048;

  __shared__ __align__(16) ushortT Ks[64 * 64];
  __shared__ __align__(16) ushortT Vs[64 * 64];
  __shared__ float fPs[4][32];
  float* fP = fPs[wave];

  bf16x8s qf[4];
#pragma unroll
  for (int s = 0; s < 4; ++s)
    qf[s] = *(const bf16x8s*)(Q + l31 * 64 + s * 16 + hi * 8);

  f32x16 o[2];
#pragma unroll
  for (int n = 0; n < 2; ++n)
#pragma unroll
    for (int r = 0; r < 16; ++r) o[n][r] = 0.f;
  float lsum = 0.f;                    // partial denominator for query l31

  const int tid = threadIdx.x;
  const int srow = tid >> 3;           // 0..31
  const int sc8  = (tid & 7) << 3;     // logical chunk (global side logical)
  const int swz  = (((tid & 7) ^ (srow & 7)) << 3);   // swizzled LDS offset
  const ushortT* Kg = K + (size_t)srow * 64 + sc8;
  const ushortT* Vg = V + (size_t)srow * 2048 + sc8;

  // preload tile kt=0 into regs
  bf16x8s kch[2], vch[2];
  kch[0] = *(const bf16x8s*)(Kg);
  kch[1] = *(const bf16x8s*)(Kg + 32 * 64);
  vch[0] = *(const bf16x8s*)(Vg);
  vch[1] = *(const bf16x8s*)(Vg + 32 * 2048);

  for (int kt = 0; kt < 2048; kt += 64) {
    __syncthreads();                    // previous iteration's readers done
    *(bf16x8s*)(Ks + srow * 64 + swz)        = kch[0];
    *(bf16x8s*)(Ks + (srow + 32) * 64 + swz) = kch[1];
    *(bf16x8s*)(Vs + srow * 64 + swz)        = vch[0];
    *(bf16x8s*)(Vs + (srow + 32) * 64 + swz) = vch[1];
    __syncthreads();                    // staging visible

    // ---- prefetch next tile (wraps to 0 on last iter; harmless) ----
    const int ktn = (kt + 64) & 2047;
    kch[0] = *(const bf16x8s*)(Kg + (size_t)ktn * 64);
    kch[1] = *(const bf16x8s*)(Kg + (size_t)(ktn + 32) * 64);
    vch[0] = *(const bf16x8s*)(Vg + ktn);
    vch[1] = *(const bf16x8s*)(Vg + 32 * 2048 + ktn);

    // ---- S^T = K·Q^T : 2 key-blocks x 4 d-slices of 32x32x16 ----
    f32x16 sacc[2];
#pragma unroll
    for (int c = 0; c < 2; ++c)
#pragma unroll
      for (int r = 0; r < 16; ++r) sacc[c][r] = 0.f;

    __builtin_amdgcn_s_setprio(1);
#pragma unroll
    for (int s = 0; s < 4; ++s) {
      const int co = (((2 * s + hi) ^ rk7) << 3);
      const bf16x8s kf0 = *(const bf16x8s*)(Ks + l31 * 64 + co);
      const bf16x8s kf1 = *(const bf16x8s*)(Ks + (32 + l31) * 64 + co);
      sacc[0] = __builtin_amdgcn_mfma_f32_32x32x16_bf16(kf0, qf[s], sacc[0], 0, 0, 0);
      sacc[1] = __builtin_amdgcn_mfma_f32_32x32x16_bf16(kf1, qf[s], sacc[1], 0, 0, 0);
    }
    __builtin_amdgcn_s_setprio(0);

    // ---- exp + in-register P repack (cvt_pk + permlane32_swap) ----
    bf16x8s pa[4];                     // pa[sig]: keys 16*sig + 8*hi + 0..7
#pragma unroll
    for (int c = 0; c < 2; ++c) {
      unsigned w[8];
#pragma unroll
      for (int i = 0; i < 8; ++i) {
        const float e0 = __builtin_amdgcn_exp2f(sacc[c][2 * i]);
        const float e1 = __builtin_amdgcn_exp2f(sacc[c][2 * i + 1]);
        lsum += e0 + e1;
        w[i] = cvtpk_bf16(e0, e1);
      }
      permlane32_swap(w[0], w[2]);
      permlane32_swap(w[1], w[3]);
      permlane32_swap(w[4], w[6]);
      permlane32_swap(w[5], w[7]);
      uint4 p0 = {w[0], w[1], w[2], w[3]};
      uint4 p1 = {w[4], w[5], w[6], w[7]};
      pa[2 * c]     = *(bf16x8s*)&p0;
      pa[2 * c + 1] = *(bf16x8s*)&p1;
    }

    // ---- O += P·V : 4 key-slices x 2 d-tiles of 32x32x16 ----
    __builtin_amdgcn_s_setprio(1);
#pragma unroll
    for (int s = 0; s < 4; ++s) {
      const int co = (((2 * s + hi) ^ rk7) << 3);
      const bf16x8s vf0 = *(const bf16x8s*)(Vs + l31 * 64 + co);
      const bf16x8s vf1 = *(const bf16x8s*)(Vs + (32 + l31) * 64 + co);
      o[0] = __builtin_amdgcn_mfma_f32_32x32x16_bf16(pa[s], vf0, o[0], 0, 0, 0);
      o[1] = __builtin_amdgcn_mfma_f32_32x32x16_bf16(pa[s], vf1, o[1], 0, 0, 0);
    }
    __builtin_amdgcn_s_setprio(0);
  }

  // ---- denominator: lane pair (l31, hi) -> full sum; broadcast by query ---
  float s = lsum + __shfl_xor(lsum, 32);
  fP[l31] = 1.0f / s;                  // both hi-lanes write same value
  asm volatile("s_waitcnt lgkmcnt(0)" ::: "memory");
  float invr[16];
#pragma unroll
  for (int r = 0; r < 16; ++r)
    invr[r] = fP[(r & 3) + 8 * (r >> 2) + 4 * hi];

#pragma unroll
  for (int n = 0; n < 2; ++n) {
    const int dcol = h * 64 + n * 32 + l31;
#pragma unroll
    for (int r = 0; r < 16; ++r) {
      const int l = q0 + (r & 3) + 8 * (r >> 2) + 4 * hi;
      Ob[((size_t)b * 2048 + l) * 1024 + dcol] =
          (ushortT)f2bf(o[n][r] * invr[r]);
    }
  }
}

// ---------------------------------------------------------- output GEMM ----
// 128x64 tiles, grid (32,16) = 512 blocks -> 2 blocks/CU. r9: BK=64 with the
// same source-swizzled staging as proj (see gemm_core_128_bk64 comment).
__global__ __launch_bounds__(256)
void out_gemm(const ushortT* __restrict__ Ob, const ushortT* __restrict__ Wto,
              const float* __restrict__ bo, float* __restrict__ C)
{
  __shared__ __align__(16) ushortT As[128 * 64];
  __shared__ __align__(16) ushortT Bs[64 * 64];
  const int m0 = blockIdx.x * 128, n0 = blockIdx.y * 64;
  const int tid = threadIdx.x;
  const int wave = tid >> 6, lane = tid & 63;
  const int wm = (wave & 1) << 6;      // 0 / 64
  const int wn = (wave >> 1) << 5;     // 0 / 32
  const int lr = lane & 15, quad = (lane >> 4) & 3;

  f32x4 acc[4][2];
#pragma unroll
  for (int mi = 0; mi < 4; ++mi)
#pragma unroll
    for (int ni = 0; ni < 2; ++ni) acc[mi][ni] = (f32x4){0.f, 0.f, 0.f, 0.f};

  for (int k0 = 0; k0 < 1024; k0 += 64) {
    __syncthreads();
#pragma unroll
    for (int i = 0; i < 4; ++i) {      // A: 128x64 = 4 chunks/thread
      const int cc  = tid + (i << 8);
      const int row = cc >> 3;
      const int pc  = cc & 7;
      const int gko = ((pc ^ (row & 7)) << 3);
      load_lds16(Ob + (size_t)(m0 + row) * 1024 + k0 + gko, As + cc * 8);
    }
#pragma unroll
    for (int i = 0; i < 2; ++i) {      // B: 64x64 = 2 chunks/thread
      const int cc  = tid + (i << 8);
      const int row = cc >> 3;
      const int pc  = cc & 7;
      const int gko = ((pc ^ (row & 7)) << 3);
      load_lds16(Wto + (size_t)(n0 + row) * 1024 + k0 + gko, Bs + cc * 8);
    }
    __syncthreads();

#pragma unroll
    for (int kk = 0; kk < 2; ++kk) {
      const int co = (((kk * 4 + quad) ^ (lr & 7)) << 3);
      bf16x8s af[4], bfr[2];
#pragma unroll
      for (int i = 0; i < 4; ++i)
        af[i] = *(const bf16x8s*)(As + (wm + i * 16 + lr) * 64 + co);
#pragma unroll
      for (int i = 0; i < 2; ++i)
        bfr[i] = *(const bf16x8s*)(Bs + (wn + i * 16 + lr) * 64 + co);

#pragma unroll
      for (int mi = 0; mi < 4; ++mi)
#pragma unroll
        for (int ni = 0; ni < 2; ++ni)
          acc[mi][ni] = __builtin_amdgcn_mfma_f32_16x16x32_bf16(
              af[mi], bfr[ni], acc[mi][ni], 0, 0, 0);
    }
  }

  const int quad4 = lane >> 4;
#pragma unroll
  for (int ni = 0; ni < 2; ++ni) {
    const int n = n0 + wn + ni * 16 + lr;
    const float bias_v = bo[n];
#pragma unroll
    for (int mi = 0; mi < 4; ++mi) {
#pragma unroll
      for (int r = 0; r < 4; ++r) {
        const int m = m0 + wm + mi * 16 + quad4 * 4 + r;
        C[(size_t)m * 1024 + n] = acc[mi][ni][r] + bias_v;
      }
    }
  }
}

// -------------------------------------------------------------- launcher ---
extern "C" void kernel_launch(void* const* d_in, const int* in_sizes, int n_in,
                              void* d_out, int out_size, void* d_ws, size_t ws_size,
                              hipStream_t stream) {
  const float* q  = (const float*)d_in[0];
  const float* k  = (const float*)d_in[1];
  const float* v  = (const float*)d_in[2];
  const float* Wq = (const float*)d_in[3];
  const float* bq = (const float*)d_in[4];
  const float* Wk = (const float*)d_in[5];
  const float* bk = (const float*)d_in[6];
  const float* Wv = (const float*)d_in[7];
  const float* bv = (const float*)d_in[8];
  const float* Wo = (const float*)d_in[9];
  const float* bo = (const float*)d_in[10];

  char* ws = (char*)d_ws;
  ushortT* Wt = (ushortT*)(ws);                       // 8 MB (4x 1024^2 bf16)
  ushortT* Qh = (ushortT*)(ws + (size_t)(8  << 20));  // [B,H,L,64]  8 MB
  ushortT* Kh = (ushortT*)(ws + (size_t)(16 << 20));  // [B,H,L,64]  8 MB
  ushortT* Vt = (ushortT*)(ws + (size_t)(24 << 20));  // [B,H,64,L]  8 MB
  ushortT* Qc = (ushortT*)(ws + (size_t)(32 << 20));  // bf16 q; reused as Ob
  ushortT* Kc = (ushortT*)(ws + (size_t)(40 << 20));  // bf16 k   8 MB
  ushortT* Vc = (ushortT*)(ws + (size_t)(48 << 20));  // bf16 v   8 MB
  ushortT* Ob = Qc;                                   // Qc dead after proj

  prep<<<dim3(2048, 1, 7), 256, 0, stream>>>(q, k, v, Wq, Wk, Wv, Wo,
                                             Qc, Kc, Vc, Wt);
  proj_gemm<<<dim3(32, 8, 3), 256, 0, stream>>>(Qc, Kc, Vc, Wt, bq, bk, bv,
                                                Qh, Kh, Vt);
  attn_kernel<<<dim3(16, 16, 2), 256, 0, stream>>>(Qh, Kh, Vt, Ob);
  out_gemm<<<dim3(32, 16), 256, 0, stream>>>(Ob, Wt + (size_t)3 * 1024 * 1024,
                                             bo, (float*)d_out);
}

// Round 10
// 224.778 us; speedup vs baseline: 1.0335x; 1.0335x over previous
//
#include <hip/hip_runtime.h>
#include <hip/hip_bf16.h>
#include <stdint.h>
#include <stddef.h>

typedef unsigned short ushortT;
typedef __attribute__((ext_vector_type(8))) short bf16x8s;   // 8 bf16, 4 VGPRs
typedef __attribute__((ext_vector_type(4))) float f32x4;
typedef __attribute__((ext_vector_type(16))) float f32x16;

// ---------------------------------------------------------------- helpers ---

__device__ __forceinline__ short f2bf(float f) {
  unsigned u = __float_as_uint(f);
  u += 0x7FFFu + ((u >> 16) & 1u);     // RNE; finite inputs
  return (short)(u >> 16);
}

__device__ __forceinline__ bf16x8s cvt8(const float* src) {
  const float4* p = (const float4*)src;
  float4 a = p[0], b = p[1];
  bf16x8s r;
  r[0] = f2bf(a.x); r[1] = f2bf(a.y); r[2] = f2bf(a.z); r[3] = f2bf(a.w);
  r[4] = f2bf(b.x); r[5] = f2bf(b.y); r[6] = f2bf(b.z); r[7] = f2bf(b.w);
  return r;
}

// packed f32x2 -> bf16x2 (RNE), one instruction
__device__ __forceinline__ unsigned cvtpk_bf16(float lo, float hi) {
  unsigned r;
  asm("v_cvt_pk_bf16_f32 %0, %1, %2" : "=v"(r) : "v"(lo), "v"(hi));
  return r;
}

// gfx950 half-wave swap: a' = [a_lo | b_lo], b' = [a_hi | b_hi]
__device__ __forceinline__ void permlane32_swap(unsigned& a, unsigned& b) {
  asm("v_permlane32_swap_b32 %0, %1" : "+v"(a), "+v"(b));
}

__device__ __forceinline__ void load_lds16(const ushortT* g, ushortT* l) {
  __builtin_amdgcn_global_load_lds(
      (const __attribute__((address_space(1))) void*)(g),
      (__attribute__((address_space(3))) void*)(l), 16, 0, 0);
}

// ------------------------------------------------------------ prep kernel ---
// z=0..3: transpose Wq/Wk/Wv/Wo (fp32 -> bf16); z=4..6: convert q/k/v.
// W-tile path vectorized (r9, kept): float4 loads, ushort4 transposed stores.
__global__ __launch_bounds__(256)
void prep(const float* __restrict__ q, const float* __restrict__ k,
          const float* __restrict__ v,
          const float* __restrict__ Wq, const float* __restrict__ Wk,
          const float* __restrict__ Wv, const float* __restrict__ Wo,
          ushortT* __restrict__ Qc, ushortT* __restrict__ Kc,
          ushortT* __restrict__ Vc, ushortT* __restrict__ Wt)
{
  const int z = blockIdx.z;
  if (z < 4) {
    if (blockIdx.x >= 1024) return;            // 32x32 tiles over 1024^2
    __shared__ __align__(16) ushortT t[32][36]; // pitch 72B: 8B-aligned rows
    const float* W = (z == 0) ? Wq : (z == 1) ? Wk : (z == 2) ? Wv : Wo;
    ushortT* dst = Wt + (size_t)z * 1024 * 1024;
    const int x = (blockIdx.x & 31) * 32, y = (blockIdx.x >> 5) * 32;
    const int r  = threadIdx.x >> 3;           // 0..31
    const int c4 = (threadIdx.x & 7) << 2;     // 0,4,..,28
    const float4 wv = *(const float4*)(W + (size_t)(y + r) * 1024 + x + c4);
    ushort4 tv;
    tv.x = (ushortT)f2bf(wv.x); tv.y = (ushortT)f2bf(wv.y);
    tv.z = (ushortT)f2bf(wv.z); tv.w = (ushortT)f2bf(wv.w);
    *(ushort4*)&t[r][c4] = tv;
    __syncthreads();
    ushort4 o;
    o.x = t[c4 + 0][r]; o.y = t[c4 + 1][r];
    o.z = t[c4 + 2][r]; o.w = t[c4 + 3][r];
    *(ushort4*)(dst + (size_t)(x + r) * 1024 + y + c4) = o;
  } else {
    const float* src = (z == 4) ? q : (z == 5) ? k : v;
    ushortT* dst = (z == 4) ? Qc : (z == 5) ? Kc : Vc;
    const size_t i8 = ((size_t)blockIdx.x * 256 + threadIdx.x) * 8;
    *(bf16x8s*)(dst + i8) = cvt8(src + i8);
  }
}

// --------------------------------------------------------------- GEMM core --
// r8 core (BK=32), verified. LEDGER (r9): BK=64 + pre-swizzled-global source
// on this 2-barrier structure = REGRESSION (proj 53 -> 70 us; MfmaUtil 13.7%,
// VALUBusy 19% -> latency-bound). Halving barriers doesn't help when each
// barrier drains 2x the in-flight global_load_lds, and the permuted source
// costs extra coalescing transactions. Matches m131-m140: only the 8-phase
// counted-vmcnt template beats this structure, not parameter tweaks.
__device__ __forceinline__ void gemm_core_128(
    const ushortT* __restrict__ A, const ushortT* __restrict__ Bt,
    int K, ushortT* As, ushortT* Bs, f32x4 (&acc)[4][4], int m0, int n0)
{
  const int tid  = threadIdx.x;
  const int wave = tid >> 6, lane = tid & 63;
  const int wm = (wave & 1) << 6;
  const int wn = (wave >> 1) << 6;
  const int lr = lane & 15;
  const int lk = (lane >> 4) << 3;

#pragma unroll
  for (int mi = 0; mi < 4; ++mi)
#pragma unroll
    for (int ni = 0; ni < 4; ++ni)
      acc[mi][ni] = (f32x4){0.f, 0.f, 0.f, 0.f};

  for (int k0 = 0; k0 < K; k0 += 32) {
    __syncthreads();
#pragma unroll
    for (int i = 0; i < 2; ++i) {
      const int cc  = tid + (i << 8);
      const int row = cc >> 2;
      const int ko  = (cc & 3) << 3;
      load_lds16(A  + (size_t)(m0 + row) * K + k0 + ko, As + cc * 8);
      load_lds16(Bt + (size_t)(n0 + row) * K + k0 + ko, Bs + cc * 8);
    }
    __syncthreads();

    bf16x8s af[4], bfr[4];
#pragma unroll
    for (int i = 0; i < 4; ++i)
      af[i] = *(const bf16x8s*)(As + (wm + i * 16 + lr) * 32 + lk);
#pragma unroll
    for (int i = 0; i < 4; ++i)
      bfr[i] = *(const bf16x8s*)(Bs + (wn + i * 16 + lr) * 32 + lk);

#pragma unroll
    for (int mi = 0; mi < 4; ++mi)
#pragma unroll
      for (int ni = 0; ni < 4; ++ni)
        acc[mi][ni] = __builtin_amdgcn_mfma_f32_16x16x32_bf16(
            af[mi], bfr[ni], acc[mi][ni], 0, 0, 0);
  }
}

// ------------------------------------------------------ projection GEMMs ---
__global__ __launch_bounds__(256)
void proj_gemm(const ushortT* __restrict__ Qc, const ushortT* __restrict__ Kc,
               const ushortT* __restrict__ Vc, const ushortT* __restrict__ WtAll,
               const float* __restrict__ bq, const float* __restrict__ bk,
               const float* __restrict__ bv,
               ushortT* __restrict__ Qh, ushortT* __restrict__ Kh,
               ushortT* __restrict__ Vt)
{
  __shared__ __align__(16) ushortT As[128 * 32];
  __shared__ __align__(16) ushortT Bs[128 * 32];
  const int which = blockIdx.z;
  const ushortT* A  = (which == 0) ? Qc : (which == 1) ? Kc : Vc;
  const ushortT* Bt = WtAll + (size_t)which * 1024 * 1024;
  const float* bias = (which == 0) ? bq : (which == 1) ? bk : bv;
  const int m0 = blockIdx.x * 128, n0 = blockIdx.y * 128;

  f32x4 acc[4][4];
  gemm_core_128(A, Bt, 1024, As, Bs, acc, m0, n0);

  const int lane = threadIdx.x & 63, wave = threadIdx.x >> 6;
  const int wm = (wave & 1) << 6, wn = (wave >> 1) << 6;
  const int lr = lane & 15, quad = lane >> 4;
  const float QSCALE = 0.18033688011112042f;   // log2(e) / sqrt(64)

#pragma unroll
  for (int ni = 0; ni < 4; ++ni) {
    const int n = n0 + wn + ni * 16 + lr;
    const float bias_v = bias[n];
    const int h = n >> 6, d = n & 63;
#pragma unroll
    for (int mi = 0; mi < 4; ++mi) {
#pragma unroll
      for (int r = 0; r < 4; ++r) {
        const int m = m0 + wm + mi * 16 + quad * 4 + r;
        const int b = m >> 11, l = m & 2047;
        float val = acc[mi][ni][r] + bias_v;
        if (which == 0) val *= QSCALE;
        const ushortT o = (ushortT)f2bf(val);
        const size_t bh = (size_t)(b * 16 + h);
        if (which == 0)      Qh[(bh * 2048 + l) * 64 + d] = o;
        else if (which == 1) Kh[(bh * 2048 + l) * 64 + d] = o;
        else                 Vt[(bh * 64 + d) * 2048 + l] = o;
      }
    }
  }
}

// ------------------------------------------------------- flash attention ---
// r8 kernel verbatim (validated 53 us): 32x32x16 MFMAs, swapped QK^T,
// in-register P via cvt_pk + permlane32_swap (T12), pitch-64 XOR K/V LDS.
__global__ __launch_bounds__(256)
void attn_kernel(const ushortT* __restrict__ Qh, const ushortT* __restrict__ Kh,
                 const ushortT* __restrict__ Vt, ushortT* __restrict__ Ob)
{
  const int b = blockIdx.z, h = blockIdx.y, qt = blockIdx.x;
  const int bh = b * 16 + h;
  const int wave = threadIdx.x >> 6, lane = threadIdx.x & 63;
  const int l31 = lane & 31, hi = lane >> 5, rk7 = l31 & 7;
  const int q0 = qt * 128 + wave * 32;

  const ushortT* Q = Qh + ((size_t)bh * 2048 + q0) * 64;
  const ushortT* K = Kh + (size_t)bh * 2048 * 64;
  const ushortT* V = Vt + (size_t)bh * 64 * 2048;

  __shared__ __align__(16) ushortT Ks[64 * 64];
  __shared__ __align__(16) ushortT Vs[64 * 64];
  __shared__ float fPs[4][32];
  float* fP = fPs[wave];

  bf16x8s qf[4];
#pragma unroll
  for (int s = 0; s < 4; ++s)
    qf[s] = *(const bf16x8s*)(Q + l31 * 64 + s * 16 + hi * 8);

  f32x16 o[2];
#pragma unroll
  for (int n = 0; n < 2; ++n)
#pragma unroll
    for (int r = 0; r < 16; ++r) o[n][r] = 0.f;
  float lsum = 0.f;                    // partial denominator for query l31

  const int tid = threadIdx.x;
  const int srow = tid >> 3;           // 0..31
  const int sc8  = (tid & 7) << 3;     // logical chunk (global side logical)
  const int swz  = (((tid & 7) ^ (srow & 7)) << 3);   // swizzled LDS offset
  const ushortT* Kg = K + (size_t)srow * 64 + sc8;
  const ushortT* Vg = V + (size_t)srow * 2048 + sc8;

  // preload tile kt=0 into regs
  bf16x8s kch[2], vch[2];
  kch[0] = *(const bf16x8s*)(Kg);
  kch[1] = *(const bf16x8s*)(Kg + 32 * 64);
  vch[0] = *(const bf16x8s*)(Vg);
  vch[1] = *(const bf16x8s*)(Vg + 32 * 2048);

  for (int kt = 0; kt < 2048; kt += 64) {
    __syncthreads();                    // previous iteration's readers done
    *(bf16x8s*)(Ks + srow * 64 + swz)        = kch[0];
    *(bf16x8s*)(Ks + (srow + 32) * 64 + swz) = kch[1];
    *(bf16x8s*)(Vs + srow * 64 + swz)        = vch[0];
    *(bf16x8s*)(Vs + (srow + 32) * 64 + swz) = vch[1];
    __syncthreads();                    // staging visible

    // ---- prefetch next tile (wraps to 0 on last iter; harmless) ----
    const int ktn = (kt + 64) & 2047;
    kch[0] = *(const bf16x8s*)(Kg + (size_t)ktn * 64);
    kch[1] = *(const bf16x8s*)(Kg + (size_t)(ktn + 32) * 64);
    vch[0] = *(const bf16x8s*)(Vg + ktn);
    vch[1] = *(const bf16x8s*)(Vg + 32 * 2048 + ktn);

    // ---- S^T = K·Q^T : 2 key-blocks x 4 d-slices of 32x32x16 ----
    f32x16 sacc[2];
#pragma unroll
    for (int c = 0; c < 2; ++c)
#pragma unroll
      for (int r = 0; r < 16; ++r) sacc[c][r] = 0.f;

    __builtin_amdgcn_s_setprio(1);
#pragma unroll
    for (int s = 0; s < 4; ++s) {
      const int co = (((2 * s + hi) ^ rk7) << 3);
      const bf16x8s kf0 = *(const bf16x8s*)(Ks + l31 * 64 + co);
      const bf16x8s kf1 = *(const bf16x8s*)(Ks + (32 + l31) * 64 + co);
      sacc[0] = __builtin_amdgcn_mfma_f32_32x32x16_bf16(kf0, qf[s], sacc[0], 0, 0, 0);
      sacc[1] = __builtin_amdgcn_mfma_f32_32x32x16_bf16(kf1, qf[s], sacc[1], 0, 0, 0);
    }
    __builtin_amdgcn_s_setprio(0);

    // ---- exp + in-register P repack (cvt_pk + permlane32_swap) ----
    bf16x8s pa[4];                     // pa[sig]: keys 16*sig + 8*hi + 0..7
#pragma unroll
    for (int c = 0; c < 2; ++c) {
      unsigned w[8];
#pragma unroll
      for (int i = 0; i < 8; ++i) {
        const float e0 = __builtin_amdgcn_exp2f(sacc[c][2 * i]);
        const float e1 = __builtin_amdgcn_exp2f(sacc[c][2 * i + 1]);
        lsum += e0 + e1;
        w[i] = cvtpk_bf16(e0, e1);
      }
      permlane32_swap(w[0], w[2]);
      permlane32_swap(w[1], w[3]);
      permlane32_swap(w[4], w[6]);
      permlane32_swap(w[5], w[7]);
      uint4 p0 = {w[0], w[1], w[2], w[3]};
      uint4 p1 = {w[4], w[5], w[6], w[7]};
      pa[2 * c]     = *(bf16x8s*)&p0;
      pa[2 * c + 1] = *(bf16x8s*)&p1;
    }

    // ---- O += P·V : 4 key-slices x 2 d-tiles of 32x32x16 ----
    __builtin_amdgcn_s_setprio(1);
#pragma unroll
    for (int s = 0; s < 4; ++s) {
      const int co = (((2 * s + hi) ^ rk7) << 3);
      const bf16x8s vf0 = *(const bf16x8s*)(Vs + l31 * 64 + co);
      const bf16x8s vf1 = *(const bf16x8s*)(Vs + (32 + l31) * 64 + co);
      o[0] = __builtin_amdgcn_mfma_f32_32x32x16_bf16(pa[s], vf0, o[0], 0, 0, 0);
      o[1] = __builtin_amdgcn_mfma_f32_32x32x16_bf16(pa[s], vf1, o[1], 0, 0, 0);
    }
    __builtin_amdgcn_s_setprio(0);
  }

  // ---- denominator: lane pair (l31, hi) -> full sum; broadcast by query ---
  float s = lsum + __shfl_xor(lsum, 32);
  fP[l31] = 1.0f / s;                  // both hi-lanes write same value
  asm volatile("s_waitcnt lgkmcnt(0)" ::: "memory");
  float invr[16];
#pragma unroll
  for (int r = 0; r < 16; ++r)
    invr[r] = fP[(r & 3) + 8 * (r >> 2) + 4 * hi];

#pragma unroll
  for (int n = 0; n < 2; ++n) {
    const int dcol = h * 64 + n * 32 + l31;
#pragma unroll
    for (int r = 0; r < 16; ++r) {
      const int l = q0 + (r & 3) + 8 * (r >> 2) + 4 * hi;
      Ob[((size_t)b * 2048 + l) * 1024 + dcol] =
          (ushortT)f2bf(o[n][r] * invr[r]);
    }
  }
}

// ---------------------------------------------------------- output GEMM ----
// 128x64 tiles, grid (32,16) = 512 blocks -> 2 blocks/CU (r8 verbatim).
__global__ __launch_bounds__(256)
void out_gemm(const ushortT* __restrict__ Ob, const ushortT* __restrict__ Wto,
              const float* __restrict__ bo, float* __restrict__ C)
{
  __shared__ __align__(16) ushortT As[128 * 32];
  __shared__ __align__(16) ushortT Bs[64 * 32];
  const int m0 = blockIdx.x * 128, n0 = blockIdx.y * 64;
  const int tid = threadIdx.x;
  const int wave = tid >> 6, lane = tid & 63;
  const int wm = (wave & 1) << 6;      // 0 / 64
  const int wn = (wave >> 1) << 5;     // 0 / 32
  const int lr = lane & 15, lk = (lane >> 4) << 3;

  f32x4 acc[4][2];
#pragma unroll
  for (int mi = 0; mi < 4; ++mi)
#pragma unroll
    for (int ni = 0; ni < 2; ++ni) acc[mi][ni] = (f32x4){0.f, 0.f, 0.f, 0.f};

  const int row = tid >> 2;            // 0..63
  const int ko  = (tid & 3) << 3;
  for (int k0 = 0; k0 < 1024; k0 += 32) {
    __syncthreads();
    load_lds16(Ob  + (size_t)(m0 + row) * 1024 + k0 + ko,      As + row * 32 + ko);
    load_lds16(Ob  + (size_t)(m0 + 64 + row) * 1024 + k0 + ko, As + (64 + row) * 32 + ko);
    load_lds16(Wto + (size_t)(n0 + row) * 1024 + k0 + ko,      Bs + row * 32 + ko);
    __syncthreads();

    bf16x8s af[4], bfr[2];
#pragma unroll
    for (int i = 0; i < 4; ++i)
      af[i] = *(const bf16x8s*)(As + (wm + i * 16 + lr) * 32 + lk);
#pragma unroll
    for (int i = 0; i < 2; ++i)
      bfr[i] = *(const bf16x8s*)(Bs + (wn + i * 16 + lr) * 32 + lk);

#pragma unroll
    for (int mi = 0; mi < 4; ++mi)
#pragma unroll
      for (int ni = 0; ni < 2; ++ni)
        acc[mi][ni] = __builtin_amdgcn_mfma_f32_16x16x32_bf16(
            af[mi], bfr[ni], acc[mi][ni], 0, 0, 0);
  }

  const int quad = lane >> 4;
#pragma unroll
  for (int ni = 0; ni < 2; ++ni) {
    const int n = n0 + wn + ni * 16 + lr;
    const float bias_v = bo[n];
#pragma unroll
    for (int mi = 0; mi < 4; ++mi) {
#pragma unroll
      for (int r = 0; r < 4; ++r) {
        const int m = m0 + wm + mi * 16 + quad * 4 + r;
        C[(size_t)m * 1024 + n] = acc[mi][ni][r] + bias_v;
      }
    }
  }
}

// -------------------------------------------------------------- launcher ---
extern "C" void kernel_launch(void* const* d_in, const int* in_sizes, int n_in,
                              void* d_out, int out_size, void* d_ws, size_t ws_size,
                              hipStream_t stream) {
  const float* q  = (const float*)d_in[0];
  const float* k  = (const float*)d_in[1];
  const float* v  = (const float*)d_in[2];
  const float* Wq = (const float*)d_in[3];
  const float* bq = (const float*)d_in[4];
  const float* Wk = (const float*)d_in[5];
  const float* bk = (const float*)d_in[6];
  const float* Wv = (const float*)d_in[7];
  const float* bv = (const float*)d_in[8];
  const float* Wo = (const float*)d_in[9];
  const float* bo = (const float*)d_in[10];

  char* ws = (char*)d_ws;
  ushortT* Wt = (ushortT*)(ws);                       // 8 MB (4x 1024^2 bf16)
  ushortT* Qh = (ushortT*)(ws + (size_t)(8  << 20));  // [B,H,L,64]  8 MB
  ushortT* Kh = (ushortT*)(ws + (size_t)(16 << 20));  // [B,H,L,64]  8 MB
  ushortT* Vt = (ushortT*)(ws + (size_t)(24 << 20));  // [B,H,64,L]  8 MB
  ushortT* Qc = (ushortT*)(ws + (size_t)(32 << 20));  // bf16 q; reused as Ob
  ushortT* Kc = (ushortT*)(ws + (size_t)(40 << 20));  // bf16 k   8 MB
  ushortT* Vc = (ushortT*)(ws + (size_t)(48 << 20));  // bf16 v   8 MB
  ushortT* Ob = Qc;                                   // Qc dead after proj

  prep<<<dim3(2048, 1, 7), 256, 0, stream>>>(q, k, v, Wq, Wk, Wv, Wo,
                                             Qc, Kc, Vc, Wt);
  proj_gemm<<<dim3(32, 8, 3), 256, 0, stream>>>(Qc, Kc, Vc, Wt, bq, bk, bv,
                                                Qh, Kh, Vt);
  attn_kernel<<<dim3(16, 16, 2), 256, 0, stream>>>(Qh, Kh, Vt, Ob);
  out_gemm<<<dim3(32, 16), 256, 0, stream>>>(Ob, Wt + (size_t)3 * 1024 * 1024,
                                             bo, (float*)d_out);
}

// Round 11
// 222.878 us; speedup vs baseline: 1.0423x; 1.0085x over previous
//
#include <hip/hip_runtime.h>
#include <hip/hip_bf16.h>
#include <stdint.h>
#include <stddef.h>

typedef unsigned short ushortT;
typedef __attribute__((ext_vector_type(8))) short bf16x8s;   // 8 bf16, 4 VGPRs
typedef __attribute__((ext_vector_type(4))) float f32x4;
typedef __attribute__((ext_vector_type(16))) float f32x16;

// ---------------------------------------------------------------- helpers ---

__device__ __forceinline__ short f2bf(float f) {
  unsigned u = __float_as_uint(f);
  u += 0x7FFFu + ((u >> 16) & 1u);     // RNE; finite inputs
  return (short)(u >> 16);
}

__device__ __forceinline__ bf16x8s cvt8(const float* src) {
  const float4* p = (const float4*)src;
  float4 a = p[0], b = p[1];
  bf16x8s r;
  r[0] = f2bf(a.x); r[1] = f2bf(a.y); r[2] = f2bf(a.z); r[3] = f2bf(a.w);
  r[4] = f2bf(b.x); r[5] = f2bf(b.y); r[6] = f2bf(b.z); r[7] = f2bf(b.w);
  return r;
}

// packed f32x2 -> bf16x2 (RNE), one instruction
__device__ __forceinline__ unsigned cvtpk_bf16(float lo, float hi) {
  unsigned r;
  asm("v_cvt_pk_bf16_f32 %0, %1, %2" : "=v"(r) : "v"(lo), "v"(hi));
  return r;
}

// gfx950 half-wave swap: a' = [a_lo | b_lo], b' = [a_hi | b_hi]
__device__ __forceinline__ void permlane32_swap(unsigned& a, unsigned& b) {
  asm("v_permlane32_swap_b32 %0, %1" : "+v"(a), "+v"(b));
}

__device__ __forceinline__ void load_lds16(const ushortT* g, ushortT* l) {
  __builtin_amdgcn_global_load_lds(
      (const __attribute__((address_space(1))) void*)(g),
      (__attribute__((address_space(3))) void*)(l), 16, 0, 0);
}

// ------------------------------------------------------------ prep kernel ---
// z=0..3: transpose Wq/Wk/Wv/Wo (fp32 -> bf16); z=4..6: convert q/k/v.
// W-tile path vectorized (r9, kept): float4 loads, ushort4 transposed stores.
__global__ __launch_bounds__(256)
void prep(const float* __restrict__ q, const float* __restrict__ k,
          const float* __restrict__ v,
          const float* __restrict__ Wq, const float* __restrict__ Wk,
          const float* __restrict__ Wv, const float* __restrict__ Wo,
          ushortT* __restrict__ Qc, ushortT* __restrict__ Kc,
          ushortT* __restrict__ Vc, ushortT* __restrict__ Wt)
{
  const int z = blockIdx.z;
  if (z < 4) {
    if (blockIdx.x >= 1024) return;            // 32x32 tiles over 1024^2
    __shared__ __align__(16) ushortT t[32][36]; // pitch 72B: 8B-aligned rows
    const float* W = (z == 0) ? Wq : (z == 1) ? Wk : (z == 2) ? Wv : Wo;
    ushortT* dst = Wt + (size_t)z * 1024 * 1024;
    const int x = (blockIdx.x & 31) * 32, y = (blockIdx.x >> 5) * 32;
    const int r  = threadIdx.x >> 3;           // 0..31
    const int c4 = (threadIdx.x & 7) << 2;     // 0,4,..,28
    const float4 wv = *(const float4*)(W + (size_t)(y + r) * 1024 + x + c4);
    ushort4 tv;
    tv.x = (ushortT)f2bf(wv.x); tv.y = (ushortT)f2bf(wv.y);
    tv.z = (ushortT)f2bf(wv.z); tv.w = (ushortT)f2bf(wv.w);
    *(ushort4*)&t[r][c4] = tv;
    __syncthreads();
    ushort4 o;
    o.x = t[c4 + 0][r]; o.y = t[c4 + 1][r];
    o.z = t[c4 + 2][r]; o.w = t[c4 + 3][r];
    *(ushort4*)(dst + (size_t)(x + r) * 1024 + y + c4) = o;
  } else {
    const float* src = (z == 4) ? q : (z == 5) ? k : v;
    ushortT* dst = (z == 4) ? Qc : (z == 5) ? Kc : Vc;
    const size_t i8 = ((size_t)blockIdx.x * 256 + threadIdx.x) * 8;
    *(bf16x8s*)(dst + i8) = cvt8(src + i8);
  }
}

// --------------------------------------------------------------- GEMM core --
// r8 core (BK=32), verified. LEDGER (r9): BK=64 + pre-swizzled-global source
// on this 2-barrier structure = REGRESSION (proj 53 -> 70 us; latency-bound,
// each barrier drains 2x the in-flight global_load_lds). Matches m131-m140:
// only the 8-phase counted-vmcnt template beats this structure.
__device__ __forceinline__ void gemm_core_128(
    const ushortT* __restrict__ A, const ushortT* __restrict__ Bt,
    int K, ushortT* As, ushortT* Bs, f32x4 (&acc)[4][4], int m0, int n0)
{
  const int tid  = threadIdx.x;
  const int wave = tid >> 6, lane = tid & 63;
  const int wm = (wave & 1) << 6;
  const int wn = (wave >> 1) << 6;
  const int lr = lane & 15;
  const int lk = (lane >> 4) << 3;

#pragma unroll
  for (int mi = 0; mi < 4; ++mi)
#pragma unroll
    for (int ni = 0; ni < 4; ++ni)
      acc[mi][ni] = (f32x4){0.f, 0.f, 0.f, 0.f};

  for (int k0 = 0; k0 < K; k0 += 32) {
    __syncthreads();
#pragma unroll
    for (int i = 0; i < 2; ++i) {
      const int cc  = tid + (i << 8);
      const int row = cc >> 2;
      const int ko  = (cc & 3) << 3;
      load_lds16(A  + (size_t)(m0 + row) * K + k0 + ko, As + cc * 8);
      load_lds16(Bt + (size_t)(n0 + row) * K + k0 + ko, Bs + cc * 8);
    }
    __syncthreads();

    bf16x8s af[4], bfr[4];
#pragma unroll
    for (int i = 0; i < 4; ++i)
      af[i] = *(const bf16x8s*)(As + (wm + i * 16 + lr) * 32 + lk);
#pragma unroll
    for (int i = 0; i < 4; ++i)
      bfr[i] = *(const bf16x8s*)(Bs + (wn + i * 16 + lr) * 32 + lk);

#pragma unroll
    for (int mi = 0; mi < 4; ++mi)
#pragma unroll
      for (int ni = 0; ni < 4; ++ni)
        acc[mi][ni] = __builtin_amdgcn_mfma_f32_16x16x32_bf16(
            af[mi], bfr[ni], acc[mi][ni], 0, 0, 0);
  }
}

// ------------------------------------------------------ projection GEMMs ---
__global__ __launch_bounds__(256)
void proj_gemm(const ushortT* __restrict__ Qc, const ushortT* __restrict__ Kc,
               const ushortT* __restrict__ Vc, const ushortT* __restrict__ WtAll,
               const float* __restrict__ bq, const float* __restrict__ bk,
               const float* __restrict__ bv,
               ushortT* __restrict__ Qh, ushortT* __restrict__ Kh,
               ushortT* __restrict__ Vt)
{
  __shared__ __align__(16) ushortT As[128 * 32];
  __shared__ __align__(16) ushortT Bs[128 * 32];
  const int which = blockIdx.z;
  const ushortT* A  = (which == 0) ? Qc : (which == 1) ? Kc : Vc;
  const ushortT* Bt = WtAll + (size_t)which * 1024 * 1024;
  const float* bias = (which == 0) ? bq : (which == 1) ? bk : bv;
  const int m0 = blockIdx.x * 128, n0 = blockIdx.y * 128;

  f32x4 acc[4][4];
  gemm_core_128(A, Bt, 1024, As, Bs, acc, m0, n0);

  const int lane = threadIdx.x & 63, wave = threadIdx.x >> 6;
  const int wm = (wave & 1) << 6, wn = (wave >> 1) << 6;
  const int lr = lane & 15, quad = lane >> 4;
  const float QSCALE = 0.18033688011112042f;   // log2(e) / sqrt(64)

#pragma unroll
  for (int ni = 0; ni < 4; ++ni) {
    const int n = n0 + wn + ni * 16 + lr;
    const float bias_v = bias[n];
    const int h = n >> 6, d = n & 63;
#pragma unroll
    for (int mi = 0; mi < 4; ++mi) {
#pragma unroll
      for (int r = 0; r < 4; ++r) {
        const int m = m0 + wm + mi * 16 + quad * 4 + r;
        const int b = m >> 11, l = m & 2047;
        float val = acc[mi][ni][r] + bias_v;
        if (which == 0) val *= QSCALE;
        const ushortT o = (ushortT)f2bf(val);
        const size_t bh = (size_t)(b * 16 + h);
        if (which == 0)      Qh[(bh * 2048 + l) * 64 + d] = o;
        else if (which == 1) Kh[(bh * 2048 + l) * 64 + d] = o;
        else                 Vt[(bh * 64 + d) * 2048 + l] = o;
      }
    }
  }
}

// ------------------------------------------------------- flash attention ---
// r8/r10 dataflow (32x32x16 MFMAs, swapped QK^T, in-register P via cvt_pk +
// permlane32_swap, pitch-64 XOR K/V LDS). r11 changes (critical-path trim):
// 1. DOUBLE-BUFFERED K/V staging, ONE barrier/iter (write-late): issue
//    prefetch -> compute buf[cur] -> ds_write regs to buf[cur^1] -> barrier.
//    Unlike GEMM dbuf (m99/m100 null: barrier drains gload_lds vmcnt), here
//    staging is reg-based: the barrier drains only cheap ds_write lgkm, and
//    the global-load vmcnt wait lands after the whole compute phase.
// 2. sacc zero-init eliminated: persistent z16 feeds the s=0 MFMA C-operand
//    (saves 32 v_mov/iter of pure VALU on the busiest pipe).
__global__ __launch_bounds__(256)
void attn_kernel(const ushortT* __restrict__ Qh, const ushortT* __restrict__ Kh,
                 const ushortT* __restrict__ Vt, ushortT* __restrict__ Ob)
{
  const int b = blockIdx.z, h = blockIdx.y, qt = blockIdx.x;
  const int bh = b * 16 + h;
  const int wave = threadIdx.x >> 6, lane = threadIdx.x & 63;
  const int l31 = lane & 31, hi = lane >> 5, rk7 = l31 & 7;
  const int q0 = qt * 128 + wave * 32;

  const ushortT* Q = Qh + ((size_t)bh * 2048 + q0) * 64;
  const ushortT* K = Kh + (size_t)bh * 2048 * 64;
  const ushortT* V = Vt + (size_t)bh * 64 * 2048;

  __shared__ __align__(16) ushortT Ks[2][64 * 64];
  __shared__ __align__(16) ushortT Vs[2][64 * 64];
  __shared__ float fPs[4][32];
  float* fP = fPs[wave];

  bf16x8s qf[4];
#pragma unroll
  for (int s = 0; s < 4; ++s)
    qf[s] = *(const bf16x8s*)(Q + l31 * 64 + s * 16 + hi * 8);

  f32x16 o[2];
  f32x16 z16;
#pragma unroll
  for (int r = 0; r < 16; ++r) z16[r] = 0.f;
#pragma unroll
  for (int n = 0; n < 2; ++n)
#pragma unroll
    for (int r = 0; r < 16; ++r) o[n][r] = 0.f;
  float lsum = 0.f;                    // partial denominator for query l31

  const int tid = threadIdx.x;
  const int srow = tid >> 3;           // 0..31
  const int sc8  = (tid & 7) << 3;     // logical chunk (global side logical)
  const int swz  = (((tid & 7) ^ (srow & 7)) << 3);   // swizzled LDS offset
  const ushortT* Kg = K + (size_t)srow * 64 + sc8;
  const ushortT* Vg = V + (size_t)srow * 2048 + sc8;

  // stage tile kt=0 into buf 0
  bf16x8s kch[2], vch[2];
  kch[0] = *(const bf16x8s*)(Kg);
  kch[1] = *(const bf16x8s*)(Kg + 32 * 64);
  vch[0] = *(const bf16x8s*)(Vg);
  vch[1] = *(const bf16x8s*)(Vg + 32 * 2048);
  *(bf16x8s*)(Ks[0] + srow * 64 + swz)        = kch[0];
  *(bf16x8s*)(Ks[0] + (srow + 32) * 64 + swz) = kch[1];
  *(bf16x8s*)(Vs[0] + srow * 64 + swz)        = vch[0];
  *(bf16x8s*)(Vs[0] + (srow + 32) * 64 + swz) = vch[1];
  __syncthreads();

  int cur = 0;
  for (int kt = 0; kt < 2048; kt += 64) {
    // ---- issue prefetch for next tile (wraps on last iter; harmless) ----
    const int ktn = (kt + 64) & 2047;
    kch[0] = *(const bf16x8s*)(Kg + (size_t)ktn * 64);
    kch[1] = *(const bf16x8s*)(Kg + (size_t)(ktn + 32) * 64);
    vch[0] = *(const bf16x8s*)(Vg + ktn);
    vch[1] = *(const bf16x8s*)(Vg + 32 * 2048 + ktn);

    const ushortT* Ksc = Ks[cur];
    const ushortT* Vsc = Vs[cur];

    // ---- S^T = K·Q^T : 2 key-blocks x 4 d-slices of 32x32x16 ----
    f32x16 sacc[2];
    __builtin_amdgcn_s_setprio(1);
    {                                  // s = 0: C-operand = persistent zero
      const int co = ((hi ^ rk7) << 3);
      const bf16x8s kf0 = *(const bf16x8s*)(Ksc + l31 * 64 + co);
      const bf16x8s kf1 = *(const bf16x8s*)(Ksc + (32 + l31) * 64 + co);
      sacc[0] = __builtin_amdgcn_mfma_f32_32x32x16_bf16(kf0, qf[0], z16, 0, 0, 0);
      sacc[1] = __builtin_amdgcn_mfma_f32_32x32x16_bf16(kf1, qf[0], z16, 0, 0, 0);
    }
#pragma unroll
    for (int s = 1; s < 4; ++s) {
      const int co = (((2 * s + hi) ^ rk7) << 3);
      const bf16x8s kf0 = *(const bf16x8s*)(Ksc + l31 * 64 + co);
      const bf16x8s kf1 = *(const bf16x8s*)(Ksc + (32 + l31) * 64 + co);
      sacc[0] = __builtin_amdgcn_mfma_f32_32x32x16_bf16(kf0, qf[s], sacc[0], 0, 0, 0);
      sacc[1] = __builtin_amdgcn_mfma_f32_32x32x16_bf16(kf1, qf[s], sacc[1], 0, 0, 0);
    }
    __builtin_amdgcn_s_setprio(0);

    // ---- exp + in-register P repack (cvt_pk + permlane32_swap) ----
    bf16x8s pa[4];                     // pa[sig]: keys 16*sig + 8*hi + 0..7
#pragma unroll
    for (int c = 0; c < 2; ++c) {
      unsigned w[8];
#pragma unroll
      for (int i = 0; i < 8; ++i) {
        const float e0 = __builtin_amdgcn_exp2f(sacc[c][2 * i]);
        const float e1 = __builtin_amdgcn_exp2f(sacc[c][2 * i + 1]);
        lsum += e0 + e1;
        w[i] = cvtpk_bf16(e0, e1);
      }
      permlane32_swap(w[0], w[2]);
      permlane32_swap(w[1], w[3]);
      permlane32_swap(w[4], w[6]);
      permlane32_swap(w[5], w[7]);
      uint4 p0 = {w[0], w[1], w[2], w[3]};
      uint4 p1 = {w[4], w[5], w[6], w[7]};
      pa[2 * c]     = *(bf16x8s*)&p0;
      pa[2 * c + 1] = *(bf16x8s*)&p1;
    }

    // ---- O += P·V : 4 key-slices x 2 d-tiles of 32x32x16 ----
    __builtin_amdgcn_s_setprio(1);
#pragma unroll
    for (int s = 0; s < 4; ++s) {
      const int co = (((2 * s + hi) ^ rk7) << 3);
      const bf16x8s vf0 = *(const bf16x8s*)(Vsc + l31 * 64 + co);
      const bf16x8s vf1 = *(const bf16x8s*)(Vsc + (32 + l31) * 64 + co);
      o[0] = __builtin_amdgcn_mfma_f32_32x32x16_bf16(pa[s], vf0, o[0], 0, 0, 0);
      o[1] = __builtin_amdgcn_mfma_f32_32x32x16_bf16(pa[s], vf1, o[1], 0, 0, 0);
    }
    __builtin_amdgcn_s_setprio(0);

    // ---- stage next tile into the other buffer; ONE barrier/iter ----
    ushortT* Ksn = Ks[cur ^ 1];
    ushortT* Vsn = Vs[cur ^ 1];
    *(bf16x8s*)(Ksn + srow * 64 + swz)        = kch[0];
    *(bf16x8s*)(Ksn + (srow + 32) * 64 + swz) = kch[1];
    *(bf16x8s*)(Vsn + srow * 64 + swz)        = vch[0];
    *(bf16x8s*)(Vsn + (srow + 32) * 64 + swz) = vch[1];
    __syncthreads();
    cur ^= 1;
  }

  // ---- denominator: lane pair (l31, hi) -> full sum; broadcast by query ---
  float s = lsum + __shfl_xor(lsum, 32);
  fP[l31] = 1.0f / s;                  // both hi-lanes write same value
  asm volatile("s_waitcnt lgkmcnt(0)" ::: "memory");
  float invr[16];
#pragma unroll
  for (int r = 0; r < 16; ++r)
    invr[r] = fP[(r & 3) + 8 * (r >> 2) + 4 * hi];

#pragma unroll
  for (int n = 0; n < 2; ++n) {
    const int dcol = h * 64 + n * 32 + l31;
#pragma unroll
    for (int r = 0; r < 16; ++r) {
      const int l = q0 + (r & 3) + 8 * (r >> 2) + 4 * hi;
      Ob[((size_t)b * 2048 + l) * 1024 + dcol] =
          (ushortT)f2bf(o[n][r] * invr[r]);
    }
  }
}

// ---------------------------------------------------------- output GEMM ----
// 128x64 tiles, grid (32,16) = 512 blocks -> 2 blocks/CU (r8 verbatim).
__global__ __launch_bounds__(256)
void out_gemm(const ushortT* __restrict__ Ob, const ushortT* __restrict__ Wto,
              const float* __restrict__ bo, float* __restrict__ C)
{
  __shared__ __align__(16) ushortT As[128 * 32];
  __shared__ __align__(16) ushortT Bs[64 * 32];
  const int m0 = blockIdx.x * 128, n0 = blockIdx.y * 64;
  const int tid = threadIdx.x;
  const int wave = tid >> 6, lane = tid & 63;
  const int wm = (wave & 1) << 6;      // 0 / 64
  const int wn = (wave >> 1) << 5;     // 0 / 32
  const int lr = lane & 15, lk = (lane >> 4) << 3;

  f32x4 acc[4][2];
#pragma unroll
  for (int mi = 0; mi < 4; ++mi)
#pragma unroll
    for (int ni = 0; ni < 2; ++ni) acc[mi][ni] = (f32x4){0.f, 0.f, 0.f, 0.f};

  const int row = tid >> 2;            // 0..63
  const int ko  = (tid & 3) << 3;
  for (int k0 = 0; k0 < 1024; k0 += 32) {
    __syncthreads();
    load_lds16(Ob  + (size_t)(m0 + row) * 1024 + k0 + ko,      As + row * 32 + ko);
    load_lds16(Ob  + (size_t)(m0 + 64 + row) * 1024 + k0 + ko, As + (64 + row) * 32 + ko);
    load_lds16(Wto + (size_t)(n0 + row) * 1024 + k0 + ko,      Bs + row * 32 + ko);
    __syncthreads();

    bf16x8s af[4], bfr[2];
#pragma unroll
    for (int i = 0; i < 4; ++i)
      af[i] = *(const bf16x8s*)(As + (wm + i * 16 + lr) * 32 + lk);
#pragma unroll
    for (int i = 0; i < 2; ++i)
      bfr[i] = *(const bf16x8s*)(Bs + (wn + i * 16 + lr) * 32 + lk);

#pragma unroll
    for (int mi = 0; mi < 4; ++mi)
#pragma unroll
      for (int ni = 0; ni < 2; ++ni)
        acc[mi][ni] = __builtin_amdgcn_mfma_f32_16x16x32_bf16(
            af[mi], bfr[ni], acc[mi][ni], 0, 0, 0);
  }

  const int quad = lane >> 4;
#pragma unroll
  for (int ni = 0; ni < 2; ++ni) {
    const int n = n0 + wn + ni * 16 + lr;
    const float bias_v = bo[n];
#pragma unroll
    for (int mi = 0; mi < 4; ++mi) {
#pragma unroll
      for (int r = 0; r < 4; ++r) {
        const int m = m0 + wm + mi * 16 + quad * 4 + r;
        C[(size_t)m * 1024 + n] = acc[mi][ni][r] + bias_v;
      }
    }
  }
}

// -------------------------------------------------------------- launcher ---
extern "C" void kernel_launch(void* const* d_in, const int* in_sizes, int n_in,
                              void* d_out, int out_size, void* d_ws, size_t ws_size,
                              hipStream_t stream) {
  const float* q  = (const float*)d_in[0];
  const float* k  = (const float*)d_in[1];
  const float* v  = (const float*)d_in[2];
  const float* Wq = (const float*)d_in[3];
  const float* bq = (const float*)d_in[4];
  const float* Wk = (const float*)d_in[5];
  const float* bk = (const float*)d_in[6];
  const float* Wv = (const float*)d_in[7];
  const float* bv = (const float*)d_in[8];
  const float* Wo = (const float*)d_in[9];
  const float* bo = (const float*)d_in[10];

  char* ws = (char*)d_ws;
  ushortT* Wt = (ushortT*)(ws);                       // 8 MB (4x 1024^2 bf16)
  ushortT* Qh = (ushortT*)(ws + (size_t)(8  << 20));  // [B,H,L,64]  8 MB
  ushortT* Kh = (ushortT*)(ws + (size_t)(16 << 20));  // [B,H,L,64]  8 MB
  ushortT* Vt = (ushortT*)(ws + (size_t)(24 << 20));  // [B,H,64,L]  8 MB
  ushortT* Qc = (ushortT*)(ws + (size_t)(32 << 20));  // bf16 q; reused as Ob
  ushortT* Kc = (ushortT*)(ws + (size_t)(40 << 20));  // bf16 k   8 MB
  ushortT* Vc = (ushortT*)(ws + (size_t)(48 << 20));  // bf16 v   8 MB
  ushortT* Ob = Qc;                                   // Qc dead after proj

  prep<<<dim3(2048, 1, 7), 256, 0, stream>>>(q, k, v, Wq, Wk, Wv, Wo,
                                             Qc, Kc, Vc, Wt);
  proj_gemm<<<dim3(32, 8, 3), 256, 0, stream>>>(Qc, Kc, Vc, Wt, bq, bk, bv,
                                                Qh, Kh, Vt);
  attn_kernel<<<dim3(16, 16, 2), 256, 0, stream>>>(Qh, Kh, Vt, Ob);
  out_gemm<<<dim3(32, 16), 256, 0, stream>>>(Ob, Wt + (size_t)3 * 1024 * 1024,
                                             bo, (float*)d_out);
}

// Round 12
// 220.981 us; speedup vs baseline: 1.0513x; 1.0086x over previous
//
#include <hip/hip_runtime.h>
#include <hip/hip_bf16.h>
#include <stdint.h>
#include <stddef.h>

typedef unsigned short ushortT;
typedef __attribute__((ext_vector_type(8))) short bf16x8s;   // 8 bf16, 4 VGPRs
typedef __attribute__((ext_vector_type(4))) float f32x4;
typedef __attribute__((ext_vector_type(16))) float f32x16;

// ---------------------------------------------------------------- helpers ---

__device__ __forceinline__ short f2bf(float f) {
  unsigned u = __float_as_uint(f);
  u += 0x7FFFu + ((u >> 16) & 1u);     // RNE; finite inputs
  return (short)(u >> 16);
}

__device__ __forceinline__ bf16x8s cvt8(const float* src) {
  const float4* p = (const float4*)src;
  float4 a = p[0], b = p[1];
  bf16x8s r;
  r[0] = f2bf(a.x); r[1] = f2bf(a.y); r[2] = f2bf(a.z); r[3] = f2bf(a.w);
  r[4] = f2bf(b.x); r[5] = f2bf(b.y); r[6] = f2bf(b.z); r[7] = f2bf(b.w);
  return r;
}

// packed f32x2 -> bf16x2 (RNE), one instruction
__device__ __forceinline__ unsigned cvtpk_bf16(float lo, float hi) {
  unsigned r;
  asm("v_cvt_pk_bf16_f32 %0, %1, %2" : "=v"(r) : "v"(lo), "v"(hi));
  return r;
}

// gfx950 half-wave swap: a' = [a_lo | b_lo], b' = [a_hi | b_hi]
__device__ __forceinline__ void permlane32_swap(unsigned& a, unsigned& b) {
  asm("v_permlane32_swap_b32 %0, %1" : "+v"(a), "+v"(b));
}

__device__ __forceinline__ void load_lds16(const ushortT* g, ushortT* l) {
  __builtin_amdgcn_global_load_lds(
      (const __attribute__((address_space(1))) void*)(g),
      (__attribute__((address_space(3))) void*)(l), 16, 0, 0);
}

// ------------------------------------------------------------ prep kernel ---
// z=0..3: transpose Wq/Wk/Wv/Wo (fp32 -> bf16); z=4..6: convert q/k/v.
// W-tile path vectorized (r9, kept): float4 loads, ushort4 transposed stores.
__global__ __launch_bounds__(256)
void prep(const float* __restrict__ q, const float* __restrict__ k,
          const float* __restrict__ v,
          const float* __restrict__ Wq, const float* __restrict__ Wk,
          const float* __restrict__ Wv, const float* __restrict__ Wo,
          ushortT* __restrict__ Qc, ushortT* __restrict__ Kc,
          ushortT* __restrict__ Vc, ushortT* __restrict__ Wt)
{
  const int z = blockIdx.z;
  if (z < 4) {
    if (blockIdx.x >= 1024) return;            // 32x32 tiles over 1024^2
    __shared__ __align__(16) ushortT t[32][36]; // pitch 72B: 8B-aligned rows
    const float* W = (z == 0) ? Wq : (z == 1) ? Wk : (z == 2) ? Wv : Wo;
    ushortT* dst = Wt + (size_t)z * 1024 * 1024;
    const int x = (blockIdx.x & 31) * 32, y = (blockIdx.x >> 5) * 32;
    const int r  = threadIdx.x >> 3;           // 0..31
    const int c4 = (threadIdx.x & 7) << 2;     // 0,4,..,28
    const float4 wv = *(const float4*)(W + (size_t)(y + r) * 1024 + x + c4);
    ushort4 tv;
    tv.x = (ushortT)f2bf(wv.x); tv.y = (ushortT)f2bf(wv.y);
    tv.z = (ushortT)f2bf(wv.z); tv.w = (ushortT)f2bf(wv.w);
    *(ushort4*)&t[r][c4] = tv;
    __syncthreads();
    ushort4 o;
    o.x = t[c4 + 0][r]; o.y = t[c4 + 1][r];
    o.z = t[c4 + 2][r]; o.w = t[c4 + 3][r];
    *(ushort4*)(dst + (size_t)(x + r) * 1024 + y + c4) = o;
  } else {
    const float* src = (z == 4) ? q : (z == 5) ? k : v;
    ushortT* dst = (z == 4) ? Qc : (z == 5) ? Kc : Vc;
    const size_t i8 = ((size_t)blockIdx.x * 256 + threadIdx.x) * 8;
    *(bf16x8s*)(dst + i8) = cvt8(src + i8);
  }
}

// --------------------------------------------------------------- GEMM core --
// r8 core (BK=32), verified. LEDGER (r9): BK=64 + pre-swizzled-global source
// on this 2-barrier structure = REGRESSION (proj 53 -> 70 us; latency-bound,
// each barrier drains 2x the in-flight global_load_lds). Matches m131-m140:
// only the 8-phase counted-vmcnt template beats this structure — and at
// M=4096/N=1024 its 256^2 tiling gives 64 blocks = 0.25/CU (non-viable).
__device__ __forceinline__ void gemm_core_128(
    const ushortT* __restrict__ A, const ushortT* __restrict__ Bt,
    int K, ushortT* As, ushortT* Bs, f32x4 (&acc)[4][4], int m0, int n0)
{
  const int tid  = threadIdx.x;
  const int wave = tid >> 6, lane = tid & 63;
  const int wm = (wave & 1) << 6;
  const int wn = (wave >> 1) << 6;
  const int lr = lane & 15;
  const int lk = (lane >> 4) << 3;

#pragma unroll
  for (int mi = 0; mi < 4; ++mi)
#pragma unroll
    for (int ni = 0; ni < 4; ++ni)
      acc[mi][ni] = (f32x4){0.f, 0.f, 0.f, 0.f};

  for (int k0 = 0; k0 < K; k0 += 32) {
    __syncthreads();
#pragma unroll
    for (int i = 0; i < 2; ++i) {
      const int cc  = tid + (i << 8);
      const int row = cc >> 2;
      const int ko  = (cc & 3) << 3;
      load_lds16(A  + (size_t)(m0 + row) * K + k0 + ko, As + cc * 8);
      load_lds16(Bt + (size_t)(n0 + row) * K + k0 + ko, Bs + cc * 8);
    }
    __syncthreads();

    bf16x8s af[4], bfr[4];
#pragma unroll
    for (int i = 0; i < 4; ++i)
      af[i] = *(const bf16x8s*)(As + (wm + i * 16 + lr) * 32 + lk);
#pragma unroll
    for (int i = 0; i < 4; ++i)
      bfr[i] = *(const bf16x8s*)(Bs + (wn + i * 16 + lr) * 32 + lk);

#pragma unroll
    for (int mi = 0; mi < 4; ++mi)
#pragma unroll
      for (int ni = 0; ni < 4; ++ni)
        acc[mi][ni] = __builtin_amdgcn_mfma_f32_16x16x32_bf16(
            af[mi], bfr[ni], acc[mi][ni], 0, 0, 0);
  }
}

// ------------------------------------------------------ projection GEMMs ---
__global__ __launch_bounds__(256)
void proj_gemm(const ushortT* __restrict__ Qc, const ushortT* __restrict__ Kc,
               const ushortT* __restrict__ Vc, const ushortT* __restrict__ WtAll,
               const float* __restrict__ bq, const float* __restrict__ bk,
               const float* __restrict__ bv,
               ushortT* __restrict__ Qh, ushortT* __restrict__ Kh,
               ushortT* __restrict__ Vt)
{
  __shared__ __align__(16) ushortT As[128 * 32];
  __shared__ __align__(16) ushortT Bs[128 * 32];
  const int which = blockIdx.z;
  const ushortT* A  = (which == 0) ? Qc : (which == 1) ? Kc : Vc;
  const ushortT* Bt = WtAll + (size_t)which * 1024 * 1024;
  const float* bias = (which == 0) ? bq : (which == 1) ? bk : bv;
  const int m0 = blockIdx.x * 128, n0 = blockIdx.y * 128;

  f32x4 acc[4][4];
  gemm_core_128(A, Bt, 1024, As, Bs, acc, m0, n0);

  const int lane = threadIdx.x & 63, wave = threadIdx.x >> 6;
  const int wm = (wave & 1) << 6, wn = (wave >> 1) << 6;
  const int lr = lane & 15, quad = lane >> 4;
  const float QSCALE = 0.18033688011112042f;   // log2(e) / sqrt(64)

#pragma unroll
  for (int ni = 0; ni < 4; ++ni) {
    const int n = n0 + wn + ni * 16 + lr;
    const float bias_v = bias[n];
    const int h = n >> 6, d = n & 63;
#pragma unroll
    for (int mi = 0; mi < 4; ++mi) {
#pragma unroll
      for (int r = 0; r < 4; ++r) {
        const int m = m0 + wm + mi * 16 + quad * 4 + r;
        const int b = m >> 11, l = m & 2047;
        float val = acc[mi][ni][r] + bias_v;
        if (which == 0) val *= QSCALE;
        const ushortT o = (ushortT)f2bf(val);
        const size_t bh = (size_t)(b * 16 + h);
        if (which == 0)      Qh[(bh * 2048 + l) * 64 + d] = o;
        else if (which == 1) Kh[(bh * 2048 + l) * 64 + d] = o;
        else                 Vt[(bh * 64 + d) * 2048 + l] = o;
      }
    }
  }
}

// ------------------------------------------------------- flash attention ---
// r10 structure EXACTLY (single-buffered Ks/Vs, TWO barriers/iter, prefetch
// after staging — measured 52.3-53.0 us twice). LEDGER (r11): dbuf/one-
// barrier + z16 bundle = attn 55.3 (+2.4); dbuf convicted on mechanism
// (single barrier gates on slowest wave's full compute+vmcnt+write chain;
// two barriers keep the 4 waves phase-locked on the shared LDS pipe).
// r12 single variable: z16 zero-init elimination only — persistent zero
// vector feeds the s=0 MFMA C-operand, saving 32 v_mov/iter of pure VALU.
__global__ __launch_bounds__(256)
void attn_kernel(const ushortT* __restrict__ Qh, const ushortT* __restrict__ Kh,
                 const ushortT* __restrict__ Vt, ushortT* __restrict__ Ob)
{
  const int b = blockIdx.z, h = blockIdx.y, qt = blockIdx.x;
  const int bh = b * 16 + h;
  const int wave = threadIdx.x >> 6, lane = threadIdx.x & 63;
  const int l31 = lane & 31, hi = lane >> 5, rk7 = l31 & 7;
  const int q0 = qt * 128 + wave * 32;

  const ushortT* Q = Qh + ((size_t)bh * 2048 + q0) * 64;
  const ushortT* K = Kh + (size_t)bh * 2048 * 64;
  const ushortT* V = Vt + (size_t)bh * 64 * 2048;

  __shared__ __align__(16) ushortT Ks[64 * 64];
  __shared__ __align__(16) ushortT Vs[64 * 64];
  __shared__ float fPs[4][32];
  float* fP = fPs[wave];

  bf16x8s qf[4];
#pragma unroll
  for (int s = 0; s < 4; ++s)
    qf[s] = *(const bf16x8s*)(Q + l31 * 64 + s * 16 + hi * 8);

  f32x16 o[2];
  f32x16 z16;
#pragma unroll
  for (int r = 0; r < 16; ++r) z16[r] = 0.f;
#pragma unroll
  for (int n = 0; n < 2; ++n)
#pragma unroll
    for (int r = 0; r < 16; ++r) o[n][r] = 0.f;
  float lsum = 0.f;                    // partial denominator for query l31

  const int tid = threadIdx.x;
  const int srow = tid >> 3;           // 0..31
  const int sc8  = (tid & 7) << 3;     // logical chunk (global side logical)
  const int swz  = (((tid & 7) ^ (srow & 7)) << 3);   // swizzled LDS offset
  const ushortT* Kg = K + (size_t)srow * 64 + sc8;
  const ushortT* Vg = V + (size_t)srow * 2048 + sc8;

  // preload tile kt=0 into regs
  bf16x8s kch[2], vch[2];
  kch[0] = *(const bf16x8s*)(Kg);
  kch[1] = *(const bf16x8s*)(Kg + 32 * 64);
  vch[0] = *(const bf16x8s*)(Vg);
  vch[1] = *(const bf16x8s*)(Vg + 32 * 2048);

  for (int kt = 0; kt < 2048; kt += 64) {
    __syncthreads();                    // previous iteration's readers done
    *(bf16x8s*)(Ks + srow * 64 + swz)        = kch[0];
    *(bf16x8s*)(Ks + (srow + 32) * 64 + swz) = kch[1];
    *(bf16x8s*)(Vs + srow * 64 + swz)        = vch[0];
    *(bf16x8s*)(Vs + (srow + 32) * 64 + swz) = vch[1];
    __syncthreads();                    // staging visible

    // ---- prefetch next tile (wraps to 0 on last iter; harmless) ----
    const int ktn = (kt + 64) & 2047;
    kch[0] = *(const bf16x8s*)(Kg + (size_t)ktn * 64);
    kch[1] = *(const bf16x8s*)(Kg + (size_t)(ktn + 32) * 64);
    vch[0] = *(const bf16x8s*)(Vg + ktn);
    vch[1] = *(const bf16x8s*)(Vg + 32 * 2048 + ktn);

    // ---- S^T = K·Q^T : 2 key-blocks x 4 d-slices of 32x32x16 ----
    f32x16 sacc[2];
    __builtin_amdgcn_s_setprio(1);
    {                                  // s = 0: C-operand = persistent zero
      const int co = ((hi ^ rk7) << 3);
      const bf16x8s kf0 = *(const bf16x8s*)(Ks + l31 * 64 + co);
      const bf16x8s kf1 = *(const bf16x8s*)(Ks + (32 + l31) * 64 + co);
      sacc[0] = __builtin_amdgcn_mfma_f32_32x32x16_bf16(kf0, qf[0], z16, 0, 0, 0);
      sacc[1] = __builtin_amdgcn_mfma_f32_32x32x16_bf16(kf1, qf[0], z16, 0, 0, 0);
    }
#pragma unroll
    for (int s = 1; s < 4; ++s) {
      const int co = (((2 * s + hi) ^ rk7) << 3);
      const bf16x8s kf0 = *(const bf16x8s*)(Ks + l31 * 64 + co);
      const bf16x8s kf1 = *(const bf16x8s*)(Ks + (32 + l31) * 64 + co);
      sacc[0] = __builtin_amdgcn_mfma_f32_32x32x16_bf16(kf0, qf[s], sacc[0], 0, 0, 0);
      sacc[1] = __builtin_amdgcn_mfma_f32_32x32x16_bf16(kf1, qf[s], sacc[1], 0, 0, 0);
    }
    __builtin_amdgcn_s_setprio(0);

    // ---- exp + in-register P repack (cvt_pk + permlane32_swap) ----
    bf16x8s pa[4];                     // pa[sig]: keys 16*sig + 8*hi + 0..7
#pragma unroll
    for (int c = 0; c < 2; ++c) {
      unsigned w[8];
#pragma unroll
      for (int i = 0; i < 8; ++i) {
        const float e0 = __builtin_amdgcn_exp2f(sacc[c][2 * i]);
        const float e1 = __builtin_amdgcn_exp2f(sacc[c][2 * i + 1]);
        lsum += e0 + e1;
        w[i] = cvtpk_bf16(e0, e1);
      }
      permlane32_swap(w[0], w[2]);
      permlane32_swap(w[1], w[3]);
      permlane32_swap(w[4], w[6]);
      permlane32_swap(w[5], w[7]);
      uint4 p0 = {w[0], w[1], w[2], w[3]};
      uint4 p1 = {w[4], w[5], w[6], w[7]};
      pa[2 * c]     = *(bf16x8s*)&p0;
      pa[2 * c + 1] = *(bf16x8s*)&p1;
    }

    // ---- O += P·V : 4 key-slices x 2 d-tiles of 32x32x16 ----
    __builtin_amdgcn_s_setprio(1);
#pragma unroll
    for (int s = 0; s < 4; ++s) {
      const int co = (((2 * s + hi) ^ rk7) << 3);
      const bf16x8s vf0 = *(const bf16x8s*)(Vs + l31 * 64 + co);
      const bf16x8s vf1 = *(const bf16x8s*)(Vs + (32 + l31) * 64 + co);
      o[0] = __builtin_amdgcn_mfma_f32_32x32x16_bf16(pa[s], vf0, o[0], 0, 0, 0);
      o[1] = __builtin_amdgcn_mfma_f32_32x32x16_bf16(pa[s], vf1, o[1], 0, 0, 0);
    }
    __builtin_amdgcn_s_setprio(0);
  }

  // ---- denominator: lane pair (l31, hi) -> full sum; broadcast by query ---
  float s = lsum + __shfl_xor(lsum, 32);
  fP[l31] = 1.0f / s;                  // both hi-lanes write same value
  asm volatile("s_waitcnt lgkmcnt(0)" ::: "memory");
  float invr[16];
#pragma unroll
  for (int r = 0; r < 16; ++r)
    invr[r] = fP[(r & 3) + 8 * (r >> 2) + 4 * hi];

#pragma unroll
  for (int n = 0; n < 2; ++n) {
    const int dcol = h * 64 + n * 32 + l31;
#pragma unroll
    for (int r = 0; r < 16; ++r) {
      const int l = q0 + (r & 3) + 8 * (r >> 2) + 4 * hi;
      Ob[((size_t)b * 2048 + l) * 1024 + dcol] =
          (ushortT)f2bf(o[n][r] * invr[r]);
    }
  }
}

// ---------------------------------------------------------- output GEMM ----
// 128x64 tiles, grid (32,16) = 512 blocks -> 2 blocks/CU (r8 verbatim).
__global__ __launch_bounds__(256)
void out_gemm(const ushortT* __restrict__ Ob, const ushortT* __restrict__ Wto,
              const float* __restrict__ bo, float* __restrict__ C)
{
  __shared__ __align__(16) ushortT As[128 * 32];
  __shared__ __align__(16) ushortT Bs[64 * 32];
  const int m0 = blockIdx.x * 128, n0 = blockIdx.y * 64;
  const int tid = threadIdx.x;
  const int wave = tid >> 6, lane = tid & 63;
  const int wm = (wave & 1) << 6;      // 0 / 64
  const int wn = (wave >> 1) << 5;     // 0 / 32
  const int lr = lane & 15, lk = (lane >> 4) << 3;

  f32x4 acc[4][2];
#pragma unroll
  for (int mi = 0; mi < 4; ++mi)
#pragma unroll
    for (int ni = 0; ni < 2; ++ni) acc[mi][ni] = (f32x4){0.f, 0.f, 0.f, 0.f};

  const int row = tid >> 2;            // 0..63
  const int ko  = (tid & 3) << 3;
  for (int k0 = 0; k0 < 1024; k0 += 32) {
    __syncthreads();
    load_lds16(Ob  + (size_t)(m0 + row) * 1024 + k0 + ko,      As + row * 32 + ko);
    load_lds16(Ob  + (size_t)(m0 + 64 + row) * 1024 + k0 + ko, As + (64 + row) * 32 + ko);
    load_lds16(Wto + (size_t)(n0 + row) * 1024 + k0 + ko,      Bs + row * 32 + ko);
    __syncthreads();

    bf16x8s af[4], bfr[2];
#pragma unroll
    for (int i = 0; i < 4; ++i)
      af[i] = *(const bf16x8s*)(As + (wm + i * 16 + lr) * 32 + lk);
#pragma unroll
    for (int i = 0; i < 2; ++i)
      bfr[i] = *(const bf16x8s*)(Bs + (wn + i * 16 + lr) * 32 + lk);

#pragma unroll
    for (int mi = 0; mi < 4; ++mi)
#pragma unroll
      for (int ni = 0; ni < 2; ++ni)
        acc[mi][ni] = __builtin_amdgcn_mfma_f32_16x16x32_bf16(
            af[mi], bfr[ni], acc[mi][ni], 0, 0, 0);
  }

  const int quad = lane >> 4;
#pragma unroll
  for (int ni = 0; ni < 2; ++ni) {
    const int n = n0 + wn + ni * 16 + lr;
    const float bias_v = bo[n];
#pragma unroll
    for (int mi = 0; mi < 4; ++mi) {
#pragma unroll
      for (int r = 0; r < 4; ++r) {
        const int m = m0 + wm + mi * 16 + quad * 4 + r;
        C[(size_t)m * 1024 + n] = acc[mi][ni][r] + bias_v;
      }
    }
  }
}

// -------------------------------------------------------------- launcher ---
extern "C" void kernel_launch(void* const* d_in, const int* in_sizes, int n_in,
                              void* d_out, int out_size, void* d_ws, size_t ws_size,
                              hipStream_t stream) {
  const float* q  = (const float*)d_in[0];
  const float* k  = (const float*)d_in[1];
  const float* v  = (const float*)d_in[2];
  const float* Wq = (const float*)d_in[3];
  const float* bq = (const float*)d_in[4];
  const float* Wk = (const float*)d_in[5];
  const float* bk = (const float*)d_in[6];
  const float* Wv = (const float*)d_in[7];
  const float* bv = (const float*)d_in[8];
  const float* Wo = (const float*)d_in[9];
  const float* bo = (const float*)d_in[10];

  char* ws = (char*)d_ws;
  ushortT* Wt = (ushortT*)(ws);                       // 8 MB (4x 1024^2 bf16)
  ushortT* Qh = (ushortT*)(ws + (size_t)(8  << 20));  // [B,H,L,64]  8 MB
  ushortT* Kh = (ushortT*)(ws + (size_t)(16 << 20));  // [B,H,L,64]  8 MB
  ushortT* Vt = (ushortT*)(ws + (size_t)(24 << 20));  // [B,H,64,L]  8 MB
  ushortT* Qc = (ushortT*)(ws + (size_t)(32 << 20));  // bf16 q; reused as Ob
  ushortT* Kc = (ushortT*)(ws + (size_t)(40 << 20));  // bf16 k   8 MB
  ushortT* Vc = (ushortT*)(ws + (size_t)(48 << 20));  // bf16 v   8 MB
  ushortT* Ob = Qc;                                   // Qc dead after proj

  prep<<<dim3(2048, 1, 7), 256, 0, stream>>>(q, k, v, Wq, Wk, Wv, Wo,
                                             Qc, Kc, Vc, Wt);
  proj_gemm<<<dim3(32, 8, 3), 256, 0, stream>>>(Qc, Kc, Vc, Wt, bq, bk, bv,
                                                Qh, Kh, Vt);
  attn_kernel<<<dim3(16, 16, 2), 256, 0, stream>>>(Qh, Kh, Vt, Ob);
  out_gemm<<<dim3(32, 16), 256, 0, stream>>>(Ob, Wt + (size_t)3 * 1024 * 1024,
                                             bo, (float*)d_out);
}